// Round 1
// baseline (1079.259 us; speedup 1.0000x reference)
//
#include <hip/hip_runtime.h>
#include <math.h>

#define W_LEN 1024
#define BSZ 16
#define EMBED 512
#define NHEADS 8
#define HEAD_DIM 64
#define TOKENS (W_LEN * BSZ)
#define LN_EPS 1e-5f

// ---------------------------------------------------------------- LayerNorm
// one wave (64 lanes) per token; 4 tokens per 256-thread block
__global__ __launch_bounds__(256) void ln_kernel(
    const float* __restrict__ feat, const float* __restrict__ g,
    const float* __restrict__ b, float* __restrict__ xln)
{
    int tid   = threadIdx.x;
    int token = blockIdx.x * 4 + (tid >> 6);
    int lane  = tid & 63;
    const float* row = feat + (size_t)token * EMBED;

    float x[8];
    *(float4*)(x)     = *(const float4*)(row + lane * 4);
    *(float4*)(x + 4) = *(const float4*)(row + 256 + lane * 4);

    float sum = 0.f, ssq = 0.f;
#pragma unroll
    for (int i = 0; i < 8; i++) { sum += x[i]; ssq += x[i] * x[i]; }
#pragma unroll
    for (int off = 32; off > 0; off >>= 1) {
        sum += __shfl_xor(sum, off, 64);
        ssq += __shfl_xor(ssq, off, 64);
    }
    float mu  = sum * (1.0f / EMBED);
    float var = ssq * (1.0f / EMBED) - mu * mu;
    float rs  = rsqrtf(var + LN_EPS);

    float gg[8], bb[8], o[8];
    *(float4*)(gg)     = *(const float4*)(g + lane * 4);
    *(float4*)(gg + 4) = *(const float4*)(g + 256 + lane * 4);
    *(float4*)(bb)     = *(const float4*)(b + lane * 4);
    *(float4*)(bb + 4) = *(const float4*)(b + 256 + lane * 4);
#pragma unroll
    for (int i = 0; i < 8; i++) o[i] = (x[i] - mu) * rs * gg[i] + bb[i];

    float* orow = xln + (size_t)token * EMBED;
    *(float4*)(orow + lane * 4)       = *(const float4*)(o);
    *(float4*)(orow + 256 + lane * 4) = *(const float4*)(o + 4);
}

// ---------------------------------------------------------------- QKV GEMM
// C[i][j] = sum_k A[i][k] * Wt[j][k] + bias[j]; 64x64 tile, BK=16
// epilogue scatters into q/k/v with layout [(b*H+h)][w][d]; q scaled 0.125
__global__ __launch_bounds__(256) void qkv_gemm(
    const float* __restrict__ A, const float* __restrict__ Wt,
    const float* __restrict__ bias, float* __restrict__ qout,
    float* __restrict__ kout, float* __restrict__ vout)
{
    __shared__ float As[16][68];
    __shared__ float Bs[16][68];
    int t  = threadIdx.x;
    int i0 = blockIdx.x * 64, j0 = blockIdx.y * 64;
    int ti = t >> 4, tj = t & 15;
    int lr = t >> 2, lc = t & 3;

    float acc[4][4] = {};
    for (int k0 = 0; k0 < EMBED; k0 += 16) {
        float4 av = *(const float4*)(A  + (size_t)(i0 + lr) * EMBED + k0 + lc * 4);
        float4 bv = *(const float4*)(Wt + (size_t)(j0 + lr) * EMBED + k0 + lc * 4);
        __syncthreads();
        As[lc * 4 + 0][lr] = av.x; As[lc * 4 + 1][lr] = av.y;
        As[lc * 4 + 2][lr] = av.z; As[lc * 4 + 3][lr] = av.w;
        Bs[lc * 4 + 0][lr] = bv.x; Bs[lc * 4 + 1][lr] = bv.y;
        Bs[lc * 4 + 2][lr] = bv.z; Bs[lc * 4 + 3][lr] = bv.w;
        __syncthreads();
#pragma unroll
        for (int kk = 0; kk < 16; kk++) {
            float4 a = *(const float4*)&As[kk][ti * 4];
            float4 b = *(const float4*)&Bs[kk][tj * 4];
            float aa[4] = {a.x, a.y, a.z, a.w};
            float bbv[4] = {b.x, b.y, b.z, b.w};
#pragma unroll
            for (int r = 0; r < 4; r++)
#pragma unroll
                for (int c = 0; c < 4; c++) acc[r][c] += aa[r] * bbv[c];
        }
    }

    // epilogue: whole 64-wide tile lies in one q/k/v segment and one head
    int seg = j0 >> 9;              // 0=q 1=k 2=v
    int h   = (j0 >> 6) & 7;
    float* outp  = (seg == 0) ? qout : ((seg == 1) ? kout : vout);
    float  scale = (seg == 0) ? 0.125f : 1.0f;
    float bj[4];
#pragma unroll
    for (int c = 0; c < 4; c++) bj[c] = bias[j0 + tj * 4 + c];
#pragma unroll
    for (int r = 0; r < 4; r++) {
        int token = i0 + ti * 4 + r;
        int w  = token >> 4;
        int b_ = token & 15;
        float4 val;
        val.x = (acc[r][0] + bj[0]) * scale;
        val.y = (acc[r][1] + bj[1]) * scale;
        val.z = (acc[r][2] + bj[2]) * scale;
        val.w = (acc[r][3] + bj[3]) * scale;
        *(float4*)(outp + (((size_t)(b_ * NHEADS + h) * W_LEN + w) << 6) + tj * 4) = val;
    }
}

// ---------------------------------------------------------------- attention
// flash-style: one block per (b*H+h, 64-row Q tile); online softmax
__global__ __launch_bounds__(256) void attn_kernel(
    const float* __restrict__ q, const float* __restrict__ k,
    const float* __restrict__ v, float* __restrict__ outp)
{
    __shared__ float Qs[64][68];   // [d][qi]
    __shared__ float Ks[64][68];   // [d][kj]
    __shared__ float Vs[64][68];   // [kj][d]
    __shared__ float Ss[64][68];   // [qi][kj]
    __shared__ float mS[64], lS[64], aS[64];

    int t  = threadIdx.x;
    int bh = blockIdx.y;
    int q0 = blockIdx.x * 64;
    const float* qp = q + ((size_t)bh * W_LEN + q0) * HEAD_DIM;
    const float* kp = k + (size_t)bh * W_LEN * HEAD_DIM;
    const float* vp = v + (size_t)bh * W_LEN * HEAD_DIM;
    int ti = t >> 4, tj = t & 15;
    int lr = t >> 2;
    int lc4 = (t & 3) * 4;

#pragma unroll
    for (int r = 0; r < 4; r++) {
        int d0 = lc4 + 16 * r;
        float4 a = *(const float4*)(qp + lr * HEAD_DIM + d0);
        Qs[d0 + 0][lr] = a.x; Qs[d0 + 1][lr] = a.y;
        Qs[d0 + 2][lr] = a.z; Qs[d0 + 3][lr] = a.w;
    }
    if (t < 64) { mS[t] = -INFINITY; lS[t] = 0.f; }

    float o_acc[4][4] = {};

    for (int kt = 0; kt < W_LEN; kt += 64) {
        __syncthreads();   // protect Ks/Vs/Ss from previous iteration readers
#pragma unroll
        for (int r = 0; r < 4; r++) {
            int d0 = lc4 + 16 * r;
            float4 a = *(const float4*)(kp + (size_t)(kt + lr) * HEAD_DIM + d0);
            Ks[d0 + 0][lr] = a.x; Ks[d0 + 1][lr] = a.y;
            Ks[d0 + 2][lr] = a.z; Ks[d0 + 3][lr] = a.w;
            float4 vv = *(const float4*)(vp + (size_t)(kt + lr) * HEAD_DIM + d0);
            *(float4*)&Vs[lr][d0] = vv;
        }
        __syncthreads();

        // S = Q K^T  (64x64)
        float s[4][4] = {};
        for (int d = 0; d < 64; d++) {
            float4 a = *(const float4*)&Qs[d][ti * 4];
            float4 b = *(const float4*)&Ks[d][tj * 4];
            float aa[4] = {a.x, a.y, a.z, a.w};
            float bbv[4] = {b.x, b.y, b.z, b.w};
#pragma unroll
            for (int r = 0; r < 4; r++)
#pragma unroll
                for (int c = 0; c < 4; c++) s[r][c] += aa[r] * bbv[c];
        }
#pragma unroll
        for (int r = 0; r < 4; r++) {
            float4 sv = {s[r][0], s[r][1], s[r][2], s[r][3]};
            *(float4*)&Ss[ti * 4 + r][tj * 4] = sv;
        }
        __syncthreads();

        // online softmax, one thread per row (wave 0)
        if (t < 64) {
            float mo = mS[t];
            float rowmax = mo;
            for (int j = 0; j < 64; j++) rowmax = fmaxf(rowmax, Ss[t][j]);
            float mn = rowmax;
            float al = __expf(mo - mn);
            float rs = 0.f;
            for (int j = 0; j < 64; j++) {
                float p = __expf(Ss[t][j] - mn);
                Ss[t][j] = p;
                rs += p;
            }
            lS[t] = lS[t] * al + rs;
            mS[t] = mn;
            aS[t] = al;
        }
        __syncthreads();

        // O = O*alpha + P V
        float al[4];
#pragma unroll
        for (int r = 0; r < 4; r++) al[r] = aS[ti * 4 + r];
#pragma unroll
        for (int r = 0; r < 4; r++)
#pragma unroll
            for (int c = 0; c < 4; c++) o_acc[r][c] *= al[r];
        for (int j = 0; j < 64; j++) {
            float4 vv = *(const float4*)&Vs[j][tj * 4];
#pragma unroll
            for (int r = 0; r < 4; r++) {
                float p = Ss[ti * 4 + r][j];
                o_acc[r][0] += p * vv.x;
                o_acc[r][1] += p * vv.y;
                o_acc[r][2] += p * vv.z;
                o_acc[r][3] += p * vv.w;
            }
        }
    }
    __syncthreads();

    // epilogue -> attn_out[token][h*64 + d]
    int b_ = bh >> 3, h = bh & 7;
#pragma unroll
    for (int r = 0; r < 4; r++) {
        int qi = ti * 4 + r;
        int w  = q0 + qi;
        float inv = 1.0f / lS[qi];
        int token = w * BSZ + b_;
        float4 val = {o_acc[r][0] * inv, o_acc[r][1] * inv,
                      o_acc[r][2] * inv, o_acc[r][3] * inv};
        *(float4*)(outp + (size_t)token * EMBED + h * HEAD_DIM + tj * 4) = val;
    }
}

// ---------------------------------------------------------------- out-proj
// C = A @ Wt^T + bias + feat (residual)
__global__ __launch_bounds__(256) void out_gemm(
    const float* __restrict__ A, const float* __restrict__ Wt,
    const float* __restrict__ bias, const float* __restrict__ feat,
    float* __restrict__ out)
{
    __shared__ float As[16][68];
    __shared__ float Bs[16][68];
    int t  = threadIdx.x;
    int i0 = blockIdx.x * 64, j0 = blockIdx.y * 64;
    int ti = t >> 4, tj = t & 15;
    int lr = t >> 2, lc = t & 3;

    float acc[4][4] = {};
    for (int k0 = 0; k0 < EMBED; k0 += 16) {
        float4 av = *(const float4*)(A  + (size_t)(i0 + lr) * EMBED + k0 + lc * 4);
        float4 bv = *(const float4*)(Wt + (size_t)(j0 + lr) * EMBED + k0 + lc * 4);
        __syncthreads();
        As[lc * 4 + 0][lr] = av.x; As[lc * 4 + 1][lr] = av.y;
        As[lc * 4 + 2][lr] = av.z; As[lc * 4 + 3][lr] = av.w;
        Bs[lc * 4 + 0][lr] = bv.x; Bs[lc * 4 + 1][lr] = bv.y;
        Bs[lc * 4 + 2][lr] = bv.z; Bs[lc * 4 + 3][lr] = bv.w;
        __syncthreads();
#pragma unroll
        for (int kk = 0; kk < 16; kk++) {
            float4 a = *(const float4*)&As[kk][ti * 4];
            float4 b = *(const float4*)&Bs[kk][tj * 4];
            float aa[4] = {a.x, a.y, a.z, a.w};
            float bbv[4] = {b.x, b.y, b.z, b.w};
#pragma unroll
            for (int r = 0; r < 4; r++)
#pragma unroll
                for (int c = 0; c < 4; c++) acc[r][c] += aa[r] * bbv[c];
        }
    }

    float bj[4];
#pragma unroll
    for (int c = 0; c < 4; c++) bj[c] = bias[j0 + tj * 4 + c];
#pragma unroll
    for (int r = 0; r < 4; r++) {
        int token = i0 + ti * 4 + r;
        const float* frow = feat + (size_t)token * EMBED + j0 + tj * 4;
        float4 fr = *(const float4*)frow;
        float4 val;
        val.x = acc[r][0] + bj[0] + fr.x;
        val.y = acc[r][1] + bj[1] + fr.y;
        val.z = acc[r][2] + bj[2] + fr.z;
        val.w = acc[r][3] + bj[3] + fr.w;
        *(float4*)(out + (size_t)token * EMBED + j0 + tj * 4) = val;
    }
}

extern "C" void kernel_launch(void* const* d_in, const int* in_sizes, int n_in,
                              void* d_out, int out_size, void* d_ws, size_t ws_size,
                              hipStream_t stream) {
    const float* feat  = (const float*)d_in[0];
    const float* in_w  = (const float*)d_in[1];
    const float* in_b  = (const float*)d_in[2];
    const float* out_w = (const float*)d_in[3];
    const float* out_b = (const float*)d_in[4];
    const float* ln_g  = (const float*)d_in[5];
    const float* ln_b  = (const float*)d_in[6];
    float* out = (float*)d_out;

    char* ws = (char*)d_ws;
    const size_t SZ = (size_t)TOKENS * EMBED * sizeof(float);   // 33.5 MB
    float* xln = (float*)ws;              // reused as attn_out after QKV GEMM
    float* qws = (float*)(ws + SZ);
    float* kws = (float*)(ws + 2 * SZ);
    float* vws = (float*)(ws + 3 * SZ);

    ln_kernel<<<TOKENS / 4, 256, 0, stream>>>(feat, ln_g, ln_b, xln);
    qkv_gemm<<<dim3(TOKENS / 64, (3 * EMBED) / 64), 256, 0, stream>>>(
        xln, in_w, in_b, qws, kws, vws);
    attn_kernel<<<dim3(W_LEN / 64, BSZ * NHEADS), 256, 0, stream>>>(
        qws, kws, vws, xln);
    out_gemm<<<dim3(TOKENS / 64, EMBED / 64), 256, 0, stream>>>(
        xln, out_w, out_b, feat, out);
}

// Round 2
// 282.266 us; speedup vs baseline: 3.8236x; 3.8236x over previous
//
#include <hip/hip_runtime.h>
#include <math.h>

#define W_LEN 1024
#define BSZ 16
#define EMBED 512
#define NHEADS 8
#define HEAD_DIM 64
#define TOKENS (W_LEN * BSZ)
#define LN_EPS 1e-5f

typedef unsigned short ushort_t;
typedef __bf16 bf16_t;
typedef bf16_t bf16x8 __attribute__((ext_vector_type(8)));
typedef float f32x4 __attribute__((ext_vector_type(4)));

__device__ inline unsigned short f2bf(float f) {
    unsigned int u = __float_as_uint(f);
    u += 0x7fffu + ((u >> 16) & 1u);   // round-to-nearest-even
    return (unsigned short)(u >> 16);
}

// ---------------------------------------------------------------- fp32 -> bf16 weight cast
__global__ __launch_bounds__(256) void cvt_f32_bf16(const float* __restrict__ src,
                                                    unsigned short* __restrict__ dst) {
    int i = (blockIdx.x * 256 + threadIdx.x) * 4;
    float4 f = *(const float4*)(src + i);
    uint2 p;
    p.x = (unsigned)f2bf(f.x) | ((unsigned)f2bf(f.y) << 16);
    p.y = (unsigned)f2bf(f.z) | ((unsigned)f2bf(f.w) << 16);
    *(uint2*)(dst + i) = p;
}

// ---------------------------------------------------------------- LayerNorm -> bf16
// one wave per token; 4 tokens per block
__global__ __launch_bounds__(256) void ln_kernel(
    const float* __restrict__ feat, const float* __restrict__ g,
    const float* __restrict__ b, unsigned short* __restrict__ xln)
{
    int tid   = threadIdx.x;
    int token = blockIdx.x * 4 + (tid >> 6);
    int lane  = tid & 63;
    const float* row = feat + (size_t)token * EMBED;

    float x[8];
    *(float4*)(x)     = *(const float4*)(row + lane * 4);
    *(float4*)(x + 4) = *(const float4*)(row + 256 + lane * 4);

    float sum = 0.f, ssq = 0.f;
#pragma unroll
    for (int i = 0; i < 8; i++) { sum += x[i]; ssq += x[i] * x[i]; }
#pragma unroll
    for (int off = 32; off > 0; off >>= 1) {
        sum += __shfl_xor(sum, off, 64);
        ssq += __shfl_xor(ssq, off, 64);
    }
    float mu  = sum * (1.0f / EMBED);
    float var = ssq * (1.0f / EMBED) - mu * mu;
    float rs  = rsqrtf(var + LN_EPS);

    float gg[8], bb[8], o[8];
    *(float4*)(gg)     = *(const float4*)(g + lane * 4);
    *(float4*)(gg + 4) = *(const float4*)(g + 256 + lane * 4);
    *(float4*)(bb)     = *(const float4*)(b + lane * 4);
    *(float4*)(bb + 4) = *(const float4*)(b + 256 + lane * 4);
#pragma unroll
    for (int i = 0; i < 8; i++) o[i] = (x[i] - mu) * rs * gg[i] + bb[i];

    unsigned short* orow = xln + (size_t)token * EMBED;
    uint2 lo, hi;
    lo.x = (unsigned)f2bf(o[0]) | ((unsigned)f2bf(o[1]) << 16);
    lo.y = (unsigned)f2bf(o[2]) | ((unsigned)f2bf(o[3]) << 16);
    hi.x = (unsigned)f2bf(o[4]) | ((unsigned)f2bf(o[5]) << 16);
    hi.y = (unsigned)f2bf(o[6]) | ((unsigned)f2bf(o[7]) << 16);
    *(uint2*)(orow + lane * 4)       = lo;
    *(uint2*)(orow + 256 + lane * 4) = hi;
}

// ---------------------------------------------------------------- MFMA GEMM core
// C[i][j] = sum_k A[i][k]*Bt[j][k]; 128x128 block tile, 4 waves each 64x64,
// BK=32 (one mfma k-step). LDS stride 40 ushorts (80 B) -> 2-way-free b128 reads.
typedef unsigned short lds_row40[40];

__device__ inline void gemm_core(const unsigned short* __restrict__ A,
                                 const unsigned short* __restrict__ Bt,
                                 int i0, int j0,
                                 lds_row40* As, lds_row40* Bs, f32x4 acc[4][4])
{
    int t = threadIdx.x;
    int wave = t >> 6, lane = t & 63, quad = lane >> 4, l16 = lane & 15;
    int wm = (wave >> 1) * 64, wn = (wave & 1) * 64;
    int srow = t >> 2, schunk = (t & 3) * 8;

    for (int k0 = 0; k0 < EMBED; k0 += 32) {
        uint4 a0 = *(const uint4*)(A  + (size_t)(i0 + srow) * EMBED + k0 + schunk);
        uint4 a1 = *(const uint4*)(A  + (size_t)(i0 + srow + 64) * EMBED + k0 + schunk);
        uint4 b0 = *(const uint4*)(Bt + (size_t)(j0 + srow) * EMBED + k0 + schunk);
        uint4 b1 = *(const uint4*)(Bt + (size_t)(j0 + srow + 64) * EMBED + k0 + schunk);
        __syncthreads();
        *(uint4*)&As[srow][schunk]      = a0;
        *(uint4*)&As[srow + 64][schunk] = a1;
        *(uint4*)&Bs[srow][schunk]      = b0;
        *(uint4*)&Bs[srow + 64][schunk] = b1;
        __syncthreads();

        bf16x8 af[4], bfr[4];
#pragma unroll
        for (int m = 0; m < 4; m++) af[m]  = *(const bf16x8*)&As[wm + m * 16 + l16][quad * 8];
#pragma unroll
        for (int n = 0; n < 4; n++) bfr[n] = *(const bf16x8*)&Bs[wn + n * 16 + l16][quad * 8];
#pragma unroll
        for (int m = 0; m < 4; m++)
#pragma unroll
            for (int n = 0; n < 4; n++)
                acc[m][n] = __builtin_amdgcn_mfma_f32_16x16x32_bf16(af[m], bfr[n], acc[m][n], 0, 0, 0);
    }
}

// ---------------------------------------------------------------- QKV GEMM (bf16 out, scatter)
__global__ __launch_bounds__(256) void qkv_gemm_mfma(
    const unsigned short* __restrict__ A, const unsigned short* __restrict__ Bt,
    const float* __restrict__ bias, unsigned short* __restrict__ qo,
    unsigned short* __restrict__ ko, unsigned short* __restrict__ vo)
{
    __shared__ unsigned short As[128][40];
    __shared__ unsigned short Bs[128][40];
    f32x4 acc[4][4];
    const f32x4 z = {0.f, 0.f, 0.f, 0.f};
#pragma unroll
    for (int m = 0; m < 4; m++)
#pragma unroll
        for (int n = 0; n < 4; n++) acc[m][n] = z;

    int i0 = blockIdx.x * 128, j0 = blockIdx.y * 128;
    gemm_core(A, Bt, i0, j0, As, Bs, acc);

    int t = threadIdx.x, wave = t >> 6, lane = t & 63, quad = lane >> 4, l16 = lane & 15;
    int wm = (wave >> 1) * 64, wn = (wave & 1) * 64;
    int seg = j0 >> 9;                       // tile lies in one of q/k/v
    unsigned short* outp = (seg == 0) ? qo : ((seg == 1) ? ko : vo);
    float scale = (seg == 0) ? 0.125f : 1.0f;

    float bj[4]; int hh[4], dd[4];
#pragma unroll
    for (int n = 0; n < 4; n++) {
        int j = j0 + wn + n * 16 + l16;
        bj[n] = bias[j];
        hh[n] = (j >> 6) & 7;
        dd[n] = j & 63;
    }
#pragma unroll
    for (int m = 0; m < 4; m++)
#pragma unroll
        for (int r = 0; r < 4; r++) {
            int token = i0 + wm + m * 16 + quad * 4 + r;
            int w  = token >> 4;
            int b_ = token & 15;
#pragma unroll
            for (int n = 0; n < 4; n++) {
                size_t idx = (((size_t)(b_ * NHEADS + hh[n]) * W_LEN + w) << 6) + dd[n];
                outp[idx] = f2bf((acc[m][n][r] + bj[n]) * scale);
            }
        }
}

// ---------------------------------------------------------------- out-proj GEMM + residual
__global__ __launch_bounds__(256) void out_gemm_mfma(
    const unsigned short* __restrict__ A, const unsigned short* __restrict__ Bt,
    const float* __restrict__ bias, const float* __restrict__ feat,
    float* __restrict__ out)
{
    __shared__ unsigned short As[128][40];
    __shared__ unsigned short Bs[128][40];
    f32x4 acc[4][4];
    const f32x4 z = {0.f, 0.f, 0.f, 0.f};
#pragma unroll
    for (int m = 0; m < 4; m++)
#pragma unroll
        for (int n = 0; n < 4; n++) acc[m][n] = z;

    int i0 = blockIdx.x * 128, j0 = blockIdx.y * 128;
    gemm_core(A, Bt, i0, j0, As, Bs, acc);

    int t = threadIdx.x, wave = t >> 6, lane = t & 63, quad = lane >> 4, l16 = lane & 15;
    int wm = (wave >> 1) * 64, wn = (wave & 1) * 64;

    float bj[4];
#pragma unroll
    for (int n = 0; n < 4; n++) bj[n] = bias[j0 + wn + n * 16 + l16];
#pragma unroll
    for (int m = 0; m < 4; m++)
#pragma unroll
        for (int r = 0; r < 4; r++) {
            int token = i0 + wm + m * 16 + quad * 4 + r;
#pragma unroll
            for (int n = 0; n < 4; n++) {
                int col = j0 + wn + n * 16 + l16;
                size_t idx = (size_t)token * EMBED + col;
                out[idx] = acc[m][n][r] + bj[n] + feat[idx];
            }
        }
}

// ---------------------------------------------------------------- flash attention, MFMA
// block = (q-tile of 128 rows, bh); 4 waves, each owns 32 Q-rows; Bc=64.
__global__ __launch_bounds__(256) void attn_mfma(
    const unsigned short* __restrict__ q, const unsigned short* __restrict__ k,
    const unsigned short* __restrict__ v, unsigned short* __restrict__ outp)
{
    __shared__ unsigned short Qs[128][72];  // [row][d], 144 B stride
    __shared__ unsigned short Ks[64][72];   // [kj][d]
    __shared__ unsigned short Vt[64][72];   // [d][kj]  (V transposed)
    __shared__ unsigned short Ps[4][32][72];// per-wave P round-trip [i][kj]

    int t = threadIdx.x, wave = t >> 6, lane = t & 63, quad = lane >> 4, l16 = lane & 15;
    int bh = blockIdx.y;
    int q0 = blockIdx.x * 128;
    const unsigned short* qp = q + ((size_t)bh * W_LEN + q0) * HEAD_DIM;
    const unsigned short* kp = k + (size_t)bh * W_LEN * HEAD_DIM;
    const unsigned short* vp = v + (size_t)bh * W_LEN * HEAD_DIM;

    // stage Q (128x64)
    {
        int qr = t >> 1, qc0 = (t & 1) * 32;
#pragma unroll
        for (int c = 0; c < 32; c += 8)
            *(uint4*)&Qs[qr][qc0 + c] = *(const uint4*)(qp + (size_t)qr * 64 + qc0 + c);
    }

    float m_st[2][4], l_st[2][4];
#pragma unroll
    for (int m = 0; m < 2; m++)
#pragma unroll
        for (int r = 0; r < 4; r++) { m_st[m][r] = -INFINITY; l_st[m][r] = 0.f; }

    f32x4 o_acc[2][4];
    const f32x4 z = {0.f, 0.f, 0.f, 0.f};
#pragma unroll
    for (int m = 0; m < 2; m++)
#pragma unroll
        for (int d = 0; d < 4; d++) o_acc[m][d] = z;

    for (int kt = 0; kt < W_LEN; kt += 64) {
        __syncthreads();   // prior-iter readers done before restaging
        // stage K tile (64x64), coalesced
        {
            int krow = t >> 2, kc = (t & 3) * 16;
            *(uint4*)&Ks[krow][kc]     = *(const uint4*)(kp + (size_t)(kt + krow) * 64 + kc);
            *(uint4*)&Ks[krow][kc + 8] = *(const uint4*)(kp + (size_t)(kt + krow) * 64 + kc + 8);
        }
        // stage V transposed: thread packs (row 2j, 2j+1) pairs into b32 column writes
        {
            int j2 = t & 31, vc = (t >> 5) * 8;
            union { uint4 u; unsigned short s[8]; } v0, v1;
            v0.u = *(const uint4*)(vp + (size_t)(kt + 2 * j2) * 64 + vc);
            v1.u = *(const uint4*)(vp + (size_t)(kt + 2 * j2 + 1) * 64 + vc);
#pragma unroll
            for (int i = 0; i < 8; i++) {
                unsigned int pk = (unsigned)v0.s[i] | ((unsigned)v1.s[i] << 16);
                *(unsigned int*)&Vt[vc + i][2 * j2] = pk;
            }
        }
        __syncthreads();

        // ---- S = Q K^T : wave rows [wave*32, wave*32+32), cols [0,64)
        f32x4 s[2][4];
#pragma unroll
        for (int m = 0; m < 2; m++)
#pragma unroll
            for (int n = 0; n < 4; n++) s[m][n] = z;
#pragma unroll
        for (int ks = 0; ks < 2; ks++) {
            bf16x8 aq[2], bk[4];
#pragma unroll
            for (int m = 0; m < 2; m++)
                aq[m] = *(const bf16x8*)&Qs[wave * 32 + m * 16 + l16][ks * 32 + quad * 8];
#pragma unroll
            for (int n = 0; n < 4; n++)
                bk[n] = *(const bf16x8*)&Ks[n * 16 + l16][ks * 32 + quad * 8];
#pragma unroll
            for (int m = 0; m < 2; m++)
#pragma unroll
                for (int n = 0; n < 4; n++)
                    s[m][n] = __builtin_amdgcn_mfma_f32_16x16x32_bf16(aq[m], bk[n], s[m][n], 0, 0, 0);
        }

        // ---- online softmax (state replicated across 16 lanes of each quad)
        float alp[2][4];
#pragma unroll
        for (int m = 0; m < 2; m++)
#pragma unroll
            for (int r = 0; r < 4; r++) {
                float mx = fmaxf(fmaxf(s[m][0][r], s[m][1][r]), fmaxf(s[m][2][r], s[m][3][r]));
#pragma unroll
                for (int off = 1; off < 16; off <<= 1) mx = fmaxf(mx, __shfl_xor(mx, off, 64));
                float mo = m_st[m][r];
                float mn = fmaxf(mo, mx);
                alp[m][r]  = __expf(mo - mn);
                m_st[m][r] = mn;
            }
#pragma unroll
        for (int m = 0; m < 2; m++)
#pragma unroll
            for (int n = 0; n < 4; n++)
#pragma unroll
                for (int r = 0; r < 4; r++)
                    s[m][n][r] = __expf(s[m][n][r] - m_st[m][r]);
#pragma unroll
        for (int m = 0; m < 2; m++)
#pragma unroll
            for (int r = 0; r < 4; r++) {
                float sm = s[m][0][r] + s[m][1][r] + s[m][2][r] + s[m][3][r];
#pragma unroll
                for (int off = 1; off < 16; off <<= 1) sm += __shfl_xor(sm, off, 64);
                l_st[m][r] = l_st[m][r] * alp[m][r] + sm;
            }

        // ---- P -> LDS (C-layout -> A-layout round trip), wave-private region
#pragma unroll
        for (int m = 0; m < 2; m++)
#pragma unroll
            for (int n = 0; n < 4; n++)
#pragma unroll
                for (int r = 0; r < 4; r++)
                    Ps[wave][m * 16 + quad * 4 + r][n * 16 + l16] = f2bf(s[m][n][r]);

        // ---- O = O*alpha + P V
#pragma unroll
        for (int m = 0; m < 2; m++)
#pragma unroll
            for (int d = 0; d < 4; d++)
#pragma unroll
                for (int r = 0; r < 4; r++) o_acc[m][d][r] *= alp[m][r];

#pragma unroll
        for (int ks = 0; ks < 2; ks++) {
            bf16x8 ap[2], bv[4];
#pragma unroll
            for (int m = 0; m < 2; m++)
                ap[m] = *(const bf16x8*)&Ps[wave][m * 16 + l16][ks * 32 + quad * 8];
#pragma unroll
            for (int d = 0; d < 4; d++)
                bv[d] = *(const bf16x8*)&Vt[d * 16 + l16][ks * 32 + quad * 8];
#pragma unroll
            for (int m = 0; m < 2; m++)
#pragma unroll
                for (int d = 0; d < 4; d++)
                    o_acc[m][d] = __builtin_amdgcn_mfma_f32_16x16x32_bf16(ap[m], bv[d], o_acc[m][d], 0, 0, 0);
        }
    }

    // ---- epilogue: O /= l, store bf16 to attn_out[token][h*64+d]
    int b_ = bh >> 3, h = bh & 7;
#pragma unroll
    for (int m = 0; m < 2; m++)
#pragma unroll
        for (int r = 0; r < 4; r++) {
            int w = q0 + wave * 32 + m * 16 + quad * 4 + r;
            int token = w * BSZ + b_;
            float inv = 1.0f / l_st[m][r];
#pragma unroll
            for (int d = 0; d < 4; d++)
                outp[(size_t)token * EMBED + h * HEAD_DIM + d * 16 + l16] =
                    f2bf(o_acc[m][d][r] * inv);
        }
}

// ---------------------------------------------------------------- launch
extern "C" void kernel_launch(void* const* d_in, const int* in_sizes, int n_in,
                              void* d_out, int out_size, void* d_ws, size_t ws_size,
                              hipStream_t stream) {
    const float* feat  = (const float*)d_in[0];
    const float* in_w  = (const float*)d_in[1];
    const float* in_b  = (const float*)d_in[2];
    const float* out_w = (const float*)d_in[3];
    const float* out_b = (const float*)d_in[4];
    const float* ln_g  = (const float*)d_in[5];
    const float* ln_b  = (const float*)d_in[6];
    float* out = (float*)d_out;

    char* ws = (char*)d_ws;
    const size_t SZB = (size_t)TOKENS * EMBED * sizeof(unsigned short);   // 16.8 MB
    unsigned short* xln = (unsigned short*)ws;
    unsigned short* qb  = (unsigned short*)(ws + SZB);
    unsigned short* kb  = (unsigned short*)(ws + 2 * SZB);
    unsigned short* vb  = (unsigned short*)(ws + 3 * SZB);
    unsigned short* ao  = (unsigned short*)(ws + 4 * SZB);
    unsigned short* wib = (unsigned short*)(ws + 5 * SZB);
    unsigned short* wob = (unsigned short*)(ws + 5 * SZB +
                                            (size_t)3 * EMBED * EMBED * sizeof(unsigned short));

    cvt_f32_bf16<<<(3 * EMBED * EMBED) / 1024, 256, 0, stream>>>(in_w, wib);
    cvt_f32_bf16<<<(EMBED * EMBED) / 1024, 256, 0, stream>>>(out_w, wob);
    ln_kernel<<<TOKENS / 4, 256, 0, stream>>>(feat, ln_g, ln_b, xln);
    qkv_gemm_mfma<<<dim3(TOKENS / 128, (3 * EMBED) / 128), 256, 0, stream>>>(
        xln, wib, in_b, qb, kb, vb);
    attn_mfma<<<dim3(W_LEN / 128, BSZ * NHEADS), 256, 0, stream>>>(qb, kb, vb, ao);
    out_gemm_mfma<<<dim3(TOKENS / 128, EMBED / 128), 256, 0, stream>>>(
        ao, wob, out_b, feat, out);
}

// Round 3
// 225.213 us; speedup vs baseline: 4.7922x; 1.2533x over previous
//
#include <hip/hip_runtime.h>
#include <math.h>

#define W_LEN 1024
#define BSZ 16
#define EMBED 512
#define NHEADS 8
#define HEAD_DIM 64
#define TOKENS (W_LEN * BSZ)
#define LN_EPS 1e-5f

typedef __bf16 bf16_t;
typedef bf16_t bf16x8 __attribute__((ext_vector_type(8)));
typedef float f32x4 __attribute__((ext_vector_type(4)));

__device__ inline unsigned short f2bf(float f) {
    unsigned int u = __float_as_uint(f);
    u += 0x7fffu + ((u >> 16) & 1u);   // round-to-nearest-even
    return (unsigned short)(u >> 16);
}

// async global->LDS, 16 B per lane; LDS dest must be wave-uniform base + lane*16
__device__ __forceinline__ void async16(const void* g, void* l) {
    __builtin_amdgcn_global_load_lds(
        (__attribute__((address_space(1))) void*)g,
        (__attribute__((address_space(3))) void*)l, 16, 0, 0);
}

// ---------------------------------------------------------------- fp32 -> bf16 weight cast
__global__ __launch_bounds__(256) void cvt_f32_bf16(const float* __restrict__ src,
                                                    unsigned short* __restrict__ dst) {
    int i = (blockIdx.x * 256 + threadIdx.x) * 4;
    float4 f = *(const float4*)(src + i);
    uint2 p;
    p.x = (unsigned)f2bf(f.x) | ((unsigned)f2bf(f.y) << 16);
    p.y = (unsigned)f2bf(f.z) | ((unsigned)f2bf(f.w) << 16);
    *(uint2*)(dst + i) = p;
}

// ---------------------------------------------------------------- LayerNorm -> bf16
__global__ __launch_bounds__(256) void ln_kernel(
    const float* __restrict__ feat, const float* __restrict__ g,
    const float* __restrict__ b, unsigned short* __restrict__ xln)
{
    int tid   = threadIdx.x;
    int token = blockIdx.x * 4 + (tid >> 6);
    int lane  = tid & 63;
    const float* row = feat + (size_t)token * EMBED;

    float x[8];
    *(float4*)(x)     = *(const float4*)(row + lane * 4);
    *(float4*)(x + 4) = *(const float4*)(row + 256 + lane * 4);

    float sum = 0.f, ssq = 0.f;
#pragma unroll
    for (int i = 0; i < 8; i++) { sum += x[i]; ssq += x[i] * x[i]; }
#pragma unroll
    for (int off = 32; off > 0; off >>= 1) {
        sum += __shfl_xor(sum, off, 64);
        ssq += __shfl_xor(ssq, off, 64);
    }
    float mu  = sum * (1.0f / EMBED);
    float var = ssq * (1.0f / EMBED) - mu * mu;
    float rs  = rsqrtf(var + LN_EPS);

    float gg[8], bb[8], o[8];
    *(float4*)(gg)     = *(const float4*)(g + lane * 4);
    *(float4*)(gg + 4) = *(const float4*)(g + 256 + lane * 4);
    *(float4*)(bb)     = *(const float4*)(b + lane * 4);
    *(float4*)(bb + 4) = *(const float4*)(b + 256 + lane * 4);
#pragma unroll
    for (int i = 0; i < 8; i++) o[i] = (x[i] - mu) * rs * gg[i] + bb[i];

    unsigned short* orow = xln + (size_t)token * EMBED;
    uint2 lo, hi;
    lo.x = (unsigned)f2bf(o[0]) | ((unsigned)f2bf(o[1]) << 16);
    lo.y = (unsigned)f2bf(o[2]) | ((unsigned)f2bf(o[3]) << 16);
    hi.x = (unsigned)f2bf(o[4]) | ((unsigned)f2bf(o[5]) << 16);
    hi.y = (unsigned)f2bf(o[6]) | ((unsigned)f2bf(o[7]) << 16);
    *(uint2*)(orow + lane * 4)       = lo;
    *(uint2*)(orow + 256 + lane * 4) = hi;
}

// ---------------------------------------------------------------- MFMA GEMM core (m97 recipe)
// 128x128 tile, 4 waves each 64x64, BK=32; unpadded LDS + global_load_lds x16
__device__ __forceinline__ void gemm_core(const unsigned short* __restrict__ A,
                                          const unsigned short* __restrict__ Bt,
                                          int i0, int j0,
                                          unsigned short (*As)[32], unsigned short (*Bs)[32],
                                          f32x4 acc[4][4])
{
    int t = threadIdx.x;
    int wave = t >> 6, lane = t & 63, quad = lane >> 4, l16 = lane & 15;
    int wm = (wave >> 1) * 64, wn = (wave & 1) * 64;
    int srow = t >> 2, scol = (t & 3) * 8;
    const unsigned short* ga0 = A  + (size_t)(i0 + srow) * EMBED + scol;
    const unsigned short* ga1 = A  + (size_t)(i0 + srow + 64) * EMBED + scol;
    const unsigned short* gb0 = Bt + (size_t)(j0 + srow) * EMBED + scol;
    const unsigned short* gb1 = Bt + (size_t)(j0 + srow + 64) * EMBED + scol;
    unsigned short* la0 = &As[srow][scol];
    unsigned short* la1 = &As[srow + 64][scol];
    unsigned short* lb0 = &Bs[srow][scol];
    unsigned short* lb1 = &Bs[srow + 64][scol];

    for (int k0 = 0; k0 < EMBED; k0 += 32) {
        __syncthreads();                    // prior-iter readers done
        async16(ga0 + k0, la0);
        async16(ga1 + k0, la1);
        async16(gb0 + k0, lb0);
        async16(gb1 + k0, lb1);
        __syncthreads();                    // vmcnt(0) drain before barrier covers the DMA

        bf16x8 af[4], bfr[4];
#pragma unroll
        for (int m = 0; m < 4; m++) af[m]  = *(const bf16x8*)&As[wm + m * 16 + l16][quad * 8];
#pragma unroll
        for (int n = 0; n < 4; n++) bfr[n] = *(const bf16x8*)&Bs[wn + n * 16 + l16][quad * 8];
#pragma unroll
        for (int m = 0; m < 4; m++)
#pragma unroll
            for (int n = 0; n < 4; n++)
                acc[m][n] = __builtin_amdgcn_mfma_f32_16x16x32_bf16(af[m], bfr[n], acc[m][n], 0, 0, 0);
    }
}

// ---------------------------------------------------------------- QKV GEMM (bf16 out, scatter)
__global__ __launch_bounds__(256) void qkv_gemm_mfma(
    const unsigned short* __restrict__ A, const unsigned short* __restrict__ Bt,
    const float* __restrict__ bias, unsigned short* __restrict__ qo,
    unsigned short* __restrict__ ko, unsigned short* __restrict__ vo)
{
    __shared__ unsigned short As[128][32];
    __shared__ unsigned short Bs[128][32];
    f32x4 acc[4][4];
    const f32x4 z = {0.f, 0.f, 0.f, 0.f};
#pragma unroll
    for (int m = 0; m < 4; m++)
#pragma unroll
        for (int n = 0; n < 4; n++) acc[m][n] = z;

    int i0 = blockIdx.x * 128, j0 = blockIdx.y * 128;
    gemm_core(A, Bt, i0, j0, As, Bs, acc);

    int t = threadIdx.x, wave = t >> 6, lane = t & 63, quad = lane >> 4, l16 = lane & 15;
    int wm = (wave >> 1) * 64, wn = (wave & 1) * 64;
    int seg = j0 >> 9;                       // tile lies wholly in one of q/k/v
    unsigned short* outp = (seg == 0) ? qo : ((seg == 1) ? ko : vo);
    float scale = (seg == 0) ? 0.125f : 1.0f;

    float bj[4]; int hh[4], dd[4];
#pragma unroll
    for (int n = 0; n < 4; n++) {
        int j = j0 + wn + n * 16 + l16;
        bj[n] = bias[j];
        hh[n] = (j >> 6) & 7;
        dd[n] = j & 63;
    }
#pragma unroll
    for (int m = 0; m < 4; m++)
#pragma unroll
        for (int r = 0; r < 4; r++) {
            int token = i0 + wm + m * 16 + quad * 4 + r;
            int w  = token >> 4;
            int b_ = token & 15;
#pragma unroll
            for (int n = 0; n < 4; n++) {
                size_t idx = (((size_t)(b_ * NHEADS + hh[n]) * W_LEN + w) << 6) + dd[n];
                outp[idx] = f2bf((acc[m][n][r] + bj[n]) * scale);
            }
        }
}

// ---------------------------------------------------------------- out-proj GEMM + residual
__global__ __launch_bounds__(256) void out_gemm_mfma(
    const unsigned short* __restrict__ A, const unsigned short* __restrict__ Bt,
    const float* __restrict__ bias, const float* __restrict__ feat,
    float* __restrict__ out)
{
    __shared__ unsigned short As[128][32];
    __shared__ unsigned short Bs[128][32];
    f32x4 acc[4][4];
    const f32x4 z = {0.f, 0.f, 0.f, 0.f};
#pragma unroll
    for (int m = 0; m < 4; m++)
#pragma unroll
        for (int n = 0; n < 4; n++) acc[m][n] = z;

    int i0 = blockIdx.x * 128, j0 = blockIdx.y * 128;
    gemm_core(A, Bt, i0, j0, As, Bs, acc);

    int t = threadIdx.x, wave = t >> 6, lane = t & 63, quad = lane >> 4, l16 = lane & 15;
    int wm = (wave >> 1) * 64, wn = (wave & 1) * 64;

    float bj[4];
#pragma unroll
    for (int n = 0; n < 4; n++) bj[n] = bias[j0 + wn + n * 16 + l16];
#pragma unroll
    for (int m = 0; m < 4; m++)
#pragma unroll
        for (int r = 0; r < 4; r++) {
            int token = i0 + wm + m * 16 + quad * 4 + r;
#pragma unroll
            for (int n = 0; n < 4; n++) {
                int col = j0 + wn + n * 16 + l16;
                size_t idx = (size_t)token * EMBED + col;
                out[idx] = acc[m][n][r] + bj[n] + feat[idx];
            }
        }
}

// ---------------------------------------------------------------- flash attention, MFMA, S^T form
// block = (128 q-rows, bh); 4 waves, each 32 q-rows; Bc=64.
// S^T = K*Q^T  (C-layout: col=lane&15 -> q-row, row=quad*4+r -> kj)
// O^T = V^T*P^T (C-layout: col -> q-row, row -> d)
__global__ __launch_bounds__(256, 4) void attn_mfma(
    const unsigned short* __restrict__ q, const unsigned short* __restrict__ k,
    const unsigned short* __restrict__ v, unsigned short* __restrict__ outp)
{
    __shared__ union {
        unsigned short Q[128][72];                 // used only during Q-frag hoist
        struct {
            unsigned short K[64][72];              // K[kj][d]
            unsigned short V[64][72];              // Vt[d][kj]
            unsigned short P[4][32][72];           // per-wave P[qrow][kj]
        } s;
    } sm;

    int t = threadIdx.x, wave = t >> 6, lane = t & 63, quad = lane >> 4, l16 = lane & 15;
    int bh = blockIdx.y;
    int q0 = blockIdx.x * 128;
    const unsigned short* qp = q + ((size_t)bh * W_LEN + q0) * HEAD_DIM;
    const unsigned short* kp = k + (size_t)bh * W_LEN * HEAD_DIM;
    const unsigned short* vp = v + (size_t)bh * W_LEN * HEAD_DIM;

    // stage Q (128x64) then hoist this wave's Q B-frags into registers
    {
        int qr = t >> 1, qc0 = (t & 1) * 32;
#pragma unroll
        for (int c = 0; c < 32; c += 8)
            *(uint4*)&sm.Q[qr][qc0 + c] = *(const uint4*)(qp + (size_t)qr * 64 + qc0 + c);
    }
    __syncthreads();
    bf16x8 qf[2][2];                               // [nt][ks]
#pragma unroll
    for (int nt = 0; nt < 2; nt++)
#pragma unroll
        for (int ks = 0; ks < 2; ks++)
            qf[nt][ks] = *(const bf16x8*)&sm.Q[wave * 32 + nt * 16 + l16][ks * 32 + quad * 8];
    __syncthreads();                               // all waves done with Q region

    float m_st[2] = {-INFINITY, -INFINITY};
    float l_st[2] = {0.f, 0.f};
    f32x4 o_acc[4][2];                             // [mtd(d)][nt(qrow)]
    const f32x4 z = {0.f, 0.f, 0.f, 0.f};
#pragma unroll
    for (int m = 0; m < 4; m++)
#pragma unroll
        for (int n = 0; n < 2; n++) o_acc[m][n] = z;

    int krow = t >> 2, kc = (t & 3) * 16;
    int j2 = t & 31, vc = (t >> 5) * 8;

    for (int kt = 0; kt < W_LEN; kt += 64) {
        // global loads first (overlap with prior compute)
        uint4 k0v = *(const uint4*)(kp + (size_t)(kt + krow) * 64 + kc);
        uint4 k1v = *(const uint4*)(kp + (size_t)(kt + krow) * 64 + kc + 8);
        union { uint4 u; unsigned short sv[8]; } v0, v1;
        v0.u = *(const uint4*)(vp + (size_t)(kt + 2 * j2) * 64 + vc);
        v1.u = *(const uint4*)(vp + (size_t)(kt + 2 * j2 + 1) * 64 + vc);
        __syncthreads();                           // prior-iter K/V readers done
        *(uint4*)&sm.s.K[krow][kc]     = k0v;
        *(uint4*)&sm.s.K[krow][kc + 8] = k1v;
#pragma unroll
        for (int i = 0; i < 8; i++) {
            unsigned int pk = (unsigned)v0.sv[i] | ((unsigned)v1.sv[i] << 16);
            *(unsigned int*)&sm.s.V[vc + i][2 * j2] = pk;   // Vt[d][kj]
        }
        __syncthreads();

        // ---- S^T = K * Q^T : s[mt][nt], rows=kj, cols=qrow
        f32x4 s[4][2];
#pragma unroll
        for (int mt = 0; mt < 4; mt++)
#pragma unroll
            for (int nt = 0; nt < 2; nt++) s[mt][nt] = z;
#pragma unroll
        for (int ks = 0; ks < 2; ks++) {
            bf16x8 kf[4];
#pragma unroll
            for (int mt = 0; mt < 4; mt++)
                kf[mt] = *(const bf16x8*)&sm.s.K[mt * 16 + l16][ks * 32 + quad * 8];
#pragma unroll
            for (int mt = 0; mt < 4; mt++)
#pragma unroll
                for (int nt = 0; nt < 2; nt++)
                    s[mt][nt] = __builtin_amdgcn_mfma_f32_16x16x32_bf16(kf[mt], qf[nt][ks], s[mt][nt], 0, 0, 0);
        }

        // ---- online softmax: q-row = lane column; reduce in-reg + 2 shuffles
        float alp[2];
#pragma unroll
        for (int nt = 0; nt < 2; nt++) {
            float mx = s[0][nt][0];
#pragma unroll
            for (int mt = 0; mt < 4; mt++)
#pragma unroll
                for (int r = 0; r < 4; r++) mx = fmaxf(mx, s[mt][nt][r]);
            mx = fmaxf(mx, __shfl_xor(mx, 16, 64));
            mx = fmaxf(mx, __shfl_xor(mx, 32, 64));
            float mn = fmaxf(m_st[nt], mx);
            alp[nt]  = __expf(m_st[nt] - mn);
            m_st[nt] = mn;
            float sum = 0.f;
#pragma unroll
            for (int mt = 0; mt < 4; mt++)
#pragma unroll
                for (int r = 0; r < 4; r++) {
                    float p = __expf(s[mt][nt][r] - mn);
                    s[mt][nt][r] = p;
                    sum += p;
                }
            sum += __shfl_xor(sum, 16, 64);
            sum += __shfl_xor(sum, 32, 64);
            l_st[nt] = l_st[nt] * alp[nt] + sum;
        }

        // ---- P -> LDS row-major [qrow][kj]; regs r are 4 consecutive kj -> b64 writes
#pragma unroll
        for (int nt = 0; nt < 2; nt++)
#pragma unroll
            for (int mt = 0; mt < 4; mt++) {
                uint2 pk;
                pk.x = (unsigned)f2bf(s[mt][nt][0]) | ((unsigned)f2bf(s[mt][nt][1]) << 16);
                pk.y = (unsigned)f2bf(s[mt][nt][2]) | ((unsigned)f2bf(s[mt][nt][3]) << 16);
                *(uint2*)&sm.s.P[wave][nt * 16 + l16][mt * 16 + quad * 4] = pk;
            }
        asm volatile("s_waitcnt lgkmcnt(0)" ::: "memory");   // wave-private P: no barrier needed

        // ---- O^T = O^T*alpha + V^T * P^T
#pragma unroll
        for (int mtd = 0; mtd < 4; mtd++)
#pragma unroll
            for (int nt = 0; nt < 2; nt++) o_acc[mtd][nt] *= alp[nt];
#pragma unroll
        for (int ks = 0; ks < 2; ks++) {
            bf16x8 vf[4], pf[2];
#pragma unroll
            for (int mtd = 0; mtd < 4; mtd++)
                vf[mtd] = *(const bf16x8*)&sm.s.V[mtd * 16 + l16][ks * 32 + quad * 8];
#pragma unroll
            for (int nt = 0; nt < 2; nt++)
                pf[nt] = *(const bf16x8*)&sm.s.P[wave][nt * 16 + l16][ks * 32 + quad * 8];
#pragma unroll
            for (int mtd = 0; mtd < 4; mtd++)
#pragma unroll
                for (int nt = 0; nt < 2; nt++)
                    o_acc[mtd][nt] = __builtin_amdgcn_mfma_f32_16x16x32_bf16(vf[mtd], pf[nt], o_acc[mtd][nt], 0, 0, 0);
        }
    }

    // ---- epilogue: O^T cols=qrow (lane), rows=d (regs): 4 consecutive d -> uint2 stores
    int b_ = bh >> 3, h = bh & 7;
#pragma unroll
    for (int nt = 0; nt < 2; nt++) {
        int w = q0 + wave * 32 + nt * 16 + l16;
        int token = w * BSZ + b_;
        float inv = 1.0f / l_st[nt];
#pragma unroll
        for (int mtd = 0; mtd < 4; mtd++) {
            uint2 pk;
            pk.x = (unsigned)f2bf(o_acc[mtd][nt][0] * inv) |
                   ((unsigned)f2bf(o_acc[mtd][nt][1] * inv) << 16);
            pk.y = (unsigned)f2bf(o_acc[mtd][nt][2] * inv) |
                   ((unsigned)f2bf(o_acc[mtd][nt][3] * inv) << 16);
            *(uint2*)(outp + (size_t)token * EMBED + h * HEAD_DIM + mtd * 16 + quad * 4) = pk;
        }
    }
}

// ---------------------------------------------------------------- launch
extern "C" void kernel_launch(void* const* d_in, const int* in_sizes, int n_in,
                              void* d_out, int out_size, void* d_ws, size_t ws_size,
                              hipStream_t stream) {
    const float* feat  = (const float*)d_in[0];
    const float* in_w  = (const float*)d_in[1];
    const float* in_b  = (const float*)d_in[2];
    const float* out_w = (const float*)d_in[3];
    const float* out_b = (const float*)d_in[4];
    const float* ln_g  = (const float*)d_in[5];
    const float* ln_b  = (const float*)d_in[6];
    float* out = (float*)d_out;

    char* ws = (char*)d_ws;
    const size_t SZB = (size_t)TOKENS * EMBED * sizeof(unsigned short);   // 16.8 MB
    unsigned short* xln = (unsigned short*)ws;
    unsigned short* qb  = (unsigned short*)(ws + SZB);
    unsigned short* kb  = (unsigned short*)(ws + 2 * SZB);
    unsigned short* vb  = (unsigned short*)(ws + 3 * SZB);
    unsigned short* ao  = (unsigned short*)(ws + 4 * SZB);
    unsigned short* wib = (unsigned short*)(ws + 5 * SZB);
    unsigned short* wob = (unsigned short*)(ws + 5 * SZB +
                                            (size_t)3 * EMBED * EMBED * sizeof(unsigned short));

    cvt_f32_bf16<<<(3 * EMBED * EMBED) / 1024, 256, 0, stream>>>(in_w, wib);
    cvt_f32_bf16<<<(EMBED * EMBED) / 1024, 256, 0, stream>>>(out_w, wob);
    ln_kernel<<<TOKENS / 4, 256, 0, stream>>>(feat, ln_g, ln_b, xln);
    qkv_gemm_mfma<<<dim3(TOKENS / 128, (3 * EMBED) / 128), 256, 0, stream>>>(
        xln, wib, in_b, qb, kb, vb);
    attn_mfma<<<dim3(W_LEN / 128, BSZ * NHEADS), 256, 0, stream>>>(qb, kb, vb, ao);
    out_gemm_mfma<<<dim3(TOKENS / 128, EMBED / 128), 256, 0, stream>>>(
        ao, wob, out_b, feat, out);
}